// Round 19
// baseline (351.514 us; speedup 1.0000x reference)
//
#include <hip/hip_runtime.h>

#define CDIV(a,b) (((a)+(b)-1)/(b))

typedef short short8v __attribute__((ext_vector_type(8)));
typedef float f32x4 __attribute__((ext_vector_type(4)));

__device__ __forceinline__ ushort f2bf(float v) {
    uint u = __float_as_uint(v);
    return (ushort)((u + 0x7FFF + ((u >> 16) & 1)) >> 16);
}

// ---------------------------------------------------------------------------
// conv0: 3->96, 64x64 -> 32x32, fully unrolled (fp32; CIN=3 not MFMA-friendly)
// ---------------------------------------------------------------------------
__global__ __launch_bounds__(256) void conv3x3_c3(const float* __restrict__ in,
    const float* __restrict__ w, const float* __restrict__ bias, float* __restrict__ out)
{
    int idx = blockIdx.x * 256 + threadIdx.x;     // 10*96*32*32 = 983040 exact
    int ox = idx & 31; int t = idx >> 5;
    int oy = t & 31;   t >>= 5;
    int co = t % 96;   int b = t / 96;
    float acc = bias[co];
    const float* wp  = w + co * 27;
    const float* ipb = in + (size_t)b * 3 * 64 * 64;
    #pragma unroll
    for (int ci = 0; ci < 3; ++ci) {
        #pragma unroll
        for (int ky = 0; ky < 3; ++ky) {
            int iy = 2 * oy + ky;
            #pragma unroll
            for (int kx = 0; kx < 3; ++kx) {
                int ix = 2 * ox + kx;
                if (iy < 64 && ix < 64)
                    acc = fmaf(wp[ci * 9 + ky * 3 + kx], ipb[(ci * 64 + iy) * 64 + ix], acc);
            }
        }
    }
    out[idx] = fmaxf(acc, 0.f);
}

// ---------------------------------------------------------------------------
// Packing helpers (same verified math as before) + ONE merged prep kernel.
// ---------------------------------------------------------------------------
template<int CIN,int COUT>
__device__ __forceinline__ void pack_deconv(const float* __restrict__ w, ushort* __restrict__ Abuf, int idx)
{
    constexpr int MFR = COUT / 16, NSL = CIN / 8;
    int e = idx & 7; int t2 = idx >> 3;
    int lane = t2 & 63; t2 >>= 6;
    int s = t2 % NSL; t2 /= NSL;
    int m = t2 % MFR; int q = t2 / MFR;
    int co = m * 16 + (lane & 15);
    int k = s * 32 + (lane >> 4) * 8 + e;
    int tap = k / CIN, ci = k % CIN;
    const int widx[4][4] = {{5,7,13,15},{4,6,12,14},{1,3,9,11},{0,2,8,10}};
    Abuf[idx] = f2bf(w[((size_t)ci * COUT + co) * 16 + widx[q][tap]]);
}

template<int CIN,int COUT>
__device__ __forceinline__ void pack_conv(const float* __restrict__ w, ushort* __restrict__ Abuf, int idx)
{
    constexpr int NSL = 9 * CIN / 32;
    int e = idx & 7; int t2 = idx >> 3;
    int lane = t2 & 63; t2 >>= 6;
    int s = t2 % NSL; int m = t2 / NSL;
    int co = m * 16 + (lane & 15);
    int k = s * 32 + (lane >> 4) * 8 + e;
    int tap = k / CIN, ci = k % CIN;
    Abuf[idx] = f2bf(w[((size_t)co * CIN + ci) * 9 + tap]);
}

// sizes: d4 49152 | d3 98304 | d2 196608 | d1 393216 | d0 786432
//        c1 110592 | c2 221184 | c3 442368   total 2,297,856 -> 8976 blocks
__global__ __launch_bounds__(256) void prep_all(
    const float* __restrict__ dw4, const float* __restrict__ dw3, const float* __restrict__ dw2,
    const float* __restrict__ dw1, const float* __restrict__ dw0,
    const float* __restrict__ ew1, const float* __restrict__ ew2, const float* __restrict__ ew3,
    ushort* A4, ushort* A3, ushort* A2, ushort* A1, ushort* A0,
    ushort* C1, ushort* C2, ushort* C3)
{
    int idx = blockIdx.x * 256 + threadIdx.x;
    if (idx < 49152)  { pack_deconv< 64, 48>(dw4, A4, idx); return; }
    idx -= 49152;
    if (idx < 98304)  { pack_deconv< 96, 64>(dw3, A3, idx); return; }
    idx -= 98304;
    if (idx < 196608) { pack_deconv<128, 96>(dw2, A2, idx); return; }
    idx -= 196608;
    if (idx < 393216) { pack_deconv<192,128>(dw1, A1, idx); return; }
    idx -= 393216;
    if (idx < 786432) { pack_deconv<256,192>(dw0, A0, idx); return; }
    idx -= 786432;
    if (idx < 110592) { pack_conv< 96,128>(ew1, C1, idx); return; }
    idx -= 110592;
    if (idx < 221184) { pack_conv<128,192>(ew2, C2, idx); return; }
    idx -= 221184;
    if (idx < 442368) { pack_conv<192,256>(ew3, C3, idx); return; }
}

// ---------------------------------------------------------------------------
// Conv MFMA main (unchanged)
// ---------------------------------------------------------------------------
template<int CIN,int COUT,int HOUT>
__global__ __launch_bounds__(256) void conv_mfma_g(const float* __restrict__ X,
    const ushort* __restrict__ Abuf, const float* __restrict__ bias, float* __restrict__ out)
{
    constexpr int HIN = 2 * HOUT;
    constexpr int NSL = 9 * CIN / 32, STR = CIN + 8;
    constexpr int TW = HOUT / 4;
    __shared__ __align__(16) ushort Xs[81 * STR];
    __shared__ float sbias[COUT];
    const int tid = threadIdx.x;
    const int oy0 = (blockIdx.x / TW) * 4, ox0 = (blockIdx.x % TW) * 4;
    const int b = blockIdx.y, ms = blockIdx.z;

    const float* Xb = X + (size_t)b * CIN * HIN * HIN;
    for (int i = tid; i < CIN * 81; i += 256) {
        int ci = i / 81, p = i % 81;
        int r = p / 9, c = p % 9;
        int gy = 2 * oy0 + r, gx = 2 * ox0 + c;
        float v = 0.f;
        if (gy < HIN && gx < HIN) v = Xb[((size_t)ci * HIN + gy) * HIN + gx];
        Xs[p * STR + ci] = f2bf(v);
    }
    if (tid < COUT) sbias[tid] = bias[tid];
    __syncthreads();

    const int w = tid >> 6, lane = tid & 63;
    const int ncol = lane & 15, kg = lane >> 4;
    const int r_n = ncol >> 2, c_n = ncol & 3;

    int ptap[9];
    #pragma unroll
    for (int tp = 0; tp < 9; ++tp) {
        int ky = tp / 3, kx = tp % 3;
        ptap[tp] = ((2 * r_n + ky) * 9 + (2 * c_n + kx)) * STR;
    }

    const int m = ms * 4 + w;
    f32x4 acc = {0.f, 0.f, 0.f, 0.f};
    const ushort* ab = Abuf + ((size_t)m * NSL * 64 + lane) * 8;
    #pragma unroll
    for (int s = 0; s < NSL; ++s) {
        short8v a = *(const short8v*)(ab + (size_t)s * 64 * 8);
        int tap = (s * 32) / CIN;
        int ci0 = (s * 32) % CIN + kg * 8;
        short8v bf = *(const short8v*)(&Xs[ptap[tap] + ci0]);
        acc = __builtin_amdgcn_mfma_f32_16x16x32_bf16(a, bf, acc, 0, 0, 0);
    }
    int oy = oy0 + r_n, ox = ox0 + c_n;
    size_t base = ((size_t)(b * COUT + m * 16 + kg * 4) * HOUT + oy) * HOUT + ox;
    #pragma unroll
    for (int jj = 0; jj < 4; ++jj)
        out[base + (size_t)jj * HOUT * HOUT] = fmaxf(acc[jj] + sbias[m * 16 + kg * 4 + jj], 0.f);
}

// ---------------------------------------------------------------------------
// Deconv MFMA main with m-split MS (unchanged)
// ---------------------------------------------------------------------------
template<int CIN,int COUT,int HIN,int QPB,int MS>
__global__ __launch_bounds__(256) void deconv_mfma_g(const float* __restrict__ X,
    const ushort* __restrict__ Abuf, const float* __restrict__ bias, float* __restrict__ out)
{
    constexpr int MFR = COUT / 16, NSL = CIN / 8, STR = CIN + 8;
    constexpr int MPB = MFR / MS;
    constexpr int ZQ = 4 / QPB;
    constexpr int WOUT = 2 * HIN, PLANE = 4 * HIN * HIN;
    __shared__ __align__(16) ushort Xs[100 * STR];
    __shared__ float sbias[COUT];
    const int tid = threadIdx.x;
    constexpr int TW = HIN / 8;
    const int t0 = (blockIdx.x / TW) * 8, u0 = (blockIdx.x % TW) * 8;
    const int b = blockIdx.y;
    const int zq = blockIdx.z % ZQ;
    const int ms = blockIdx.z / ZQ;

    const float* Xb = X + (size_t)b * CIN * HIN * HIN;
    for (int i = tid; i < CIN * 100; i += 256) {
        int ci = i / 100, p = i % 100;
        int r = p / 10, c = p % 10;
        int gt = t0 - 1 + r, gu = u0 - 1 + c;
        float v = 0.f;
        if (gt >= 0 && gt < HIN && gu >= 0 && gu < HIN)
            v = Xb[((size_t)ci * HIN + gt) * HIN + gu];
        Xs[p * STR + ci] = f2bf(v);
    }
    if (tid < COUT) sbias[tid] = bias[tid];
    __syncthreads();

    const int w = tid >> 6, lane = tid & 63;
    const int ncol = lane & 15, kg = lane >> 4;
    const int r_n = 2 * w + (ncol >> 3), c_n = ncol & 7;

    #pragma unroll
    for (int qz = 0; qz < QPB; ++qz) {
        const int q = zq * QPB + qz;
        const int py = q >> 1, px = q & 1;
        int ptap[4];
        #pragma unroll
        for (int tp = 0; tp < 4; ++tp) {
            int dy = py - (tp >> 1);
            int dx = px - (tp & 1);
            ptap[tp] = ((r_n + 1 + dy) * 10 + (c_n + 1 + dx)) * STR;
        }
        #pragma unroll
        for (int mm = 0; mm < MPB; ++mm) {
            const int m = ms * MPB + mm;
            f32x4 acc = {0.f, 0.f, 0.f, 0.f};
            const ushort* ab = Abuf + (((size_t)(q * MFR + m) * NSL) * 64 + lane) * 8;
            #pragma unroll
            for (int s = 0; s < NSL; ++s) {
                short8v a = *(const short8v*)(ab + (size_t)s * 64 * 8);
                int tap = (s * 32) / CIN;
                int ci0 = (s * 32) % CIN + kg * 8;
                short8v bf = *(const short8v*)(&Xs[ptap[tap] + ci0]);
                acc = __builtin_amdgcn_mfma_f32_16x16x32_bf16(a, bf, acc, 0, 0, 0);
            }
            int t = t0 + r_n, u = u0 + c_n;
            size_t base = ((size_t)(b * COUT + m * 16 + kg * 4) * (2 * HIN) + (2 * t + py)) * WOUT + (2 * u + px);
            #pragma unroll
            for (int jj = 0; jj < 4; ++jj) {
                float v = acc[jj] + sbias[m * 16 + kg * 4 + jj];
                out[base + (size_t)jj * PLANE] = fmaxf(v, 0.f);
            }
        }
    }
}

// d0 MFMA (unchanged): whole 4x4 plane = one n-frag; grid (1,10,4)
__global__ __launch_bounds__(256) void deconv_mfma_d0(const float* __restrict__ X,
    const ushort* __restrict__ Abuf, const float* __restrict__ bias, float* __restrict__ out)
{
    constexpr int CIN = 256, COUT = 192, MFR = 12, NSL = 32, STR = CIN + 8;
    __shared__ __align__(16) ushort Xs[36 * STR];
    __shared__ float sbias[COUT];
    const int tid = threadIdx.x;
    const int b = blockIdx.y, q = blockIdx.z;

    const float* Xb = X + (size_t)b * CIN * 16;
    for (int i = tid; i < CIN * 36; i += 256) {
        int ci = i / 36, p = i % 36;
        int r = p / 6, c = p % 6;
        int gt = r - 1, gu = c - 1;
        float v = 0.f;
        if (gt >= 0 && gt < 4 && gu >= 0 && gu < 4)
            v = Xb[(ci * 4 + gt) * 4 + gu];
        Xs[p * STR + ci] = f2bf(v);
    }
    if (tid < COUT) sbias[tid] = bias[tid];
    __syncthreads();

    const int w = tid >> 6, lane = tid & 63;
    const int ncol = lane & 15, kg = lane >> 4;
    const int r_n = ncol >> 2, c_n = ncol & 3;
    const int py = q >> 1, px = q & 1;

    int ptap[4];
    #pragma unroll
    for (int tp = 0; tp < 4; ++tp) {
        int dy = py - (tp >> 1);
        int dx = px - (tp & 1);
        ptap[tp] = ((r_n + 1 + dy) * 6 + (c_n + 1 + dx)) * STR;
    }
    #pragma unroll
    for (int j = 0; j < 3; ++j) {
        const int m = w + 4 * j;
        f32x4 acc = {0.f, 0.f, 0.f, 0.f};
        const ushort* ab = Abuf + (((size_t)(q * MFR + m) * NSL) * 64 + lane) * 8;
        #pragma unroll
        for (int s = 0; s < NSL; ++s) {
            short8v a = *(const short8v*)(ab + (size_t)s * 64 * 8);
            int tap = s >> 3, ci0 = (s & 7) * 32 + kg * 8;
            short8v bf = *(const short8v*)(&Xs[ptap[tap] + ci0]);
            acc = __builtin_amdgcn_mfma_f32_16x16x32_bf16(a, bf, acc, 0, 0, 0);
        }
        size_t base = ((size_t)(b * COUT + m * 16 + kg * 4) * 8 + (2 * r_n + py)) * 8 + (2 * c_n + px);
        #pragma unroll
        for (int jj = 0; jj < 4; ++jj) {
            float v = acc[jj] + sbias[m * 16 + kg * 4 + jj];
            out[base + (size_t)jj * 64] = fmaxf(v, 0.f);
        }
    }
}

// ---------------------------------------------------------------------------
// Split-K FC (unchanged)
// ---------------------------------------------------------------------------
template<int KC>
__global__ __launch_bounds__(256) void fc_splitk(const float* __restrict__ in,
    const float* __restrict__ W, float* __restrict__ partial, int K, int N)
{
    __shared__ float s_in[10 * KC];
    const int o = blockIdx.x * 256 + threadIdx.x;
    const int k0 = blockIdx.y * KC;
    for (int i = threadIdx.x; i < 10 * KC; i += 256) {
        int b = i / KC, k = i % KC;
        s_in[i] = in[(size_t)b * K + k0 + k];
    }
    __syncthreads();

    float acc[10];
    #pragma unroll
    for (int b = 0; b < 10; ++b) acc[b] = 0.f;
    const float* wp = W + (size_t)k0 * N + o;
    #pragma unroll 4
    for (int k = 0; k < KC; ++k) {
        float wv = wp[(size_t)k * N];
        #pragma unroll
        for (int b = 0; b < 10; ++b) acc[b] = fmaf(wv, s_in[b * KC + k], acc[b]);
    }
    float* pp = partial + ((size_t)blockIdx.y * 10) * N + o;
    #pragma unroll
    for (int b = 0; b < 10; ++b) pp[(size_t)b * N] = acc[b];
}

__global__ void fc_reduce_relu(const float* __restrict__ partial, const float* __restrict__ bias,
                               float* __restrict__ out, int N, int S)
{
    int i = blockIdx.x * 256 + threadIdx.x;
    if (i >= 10 * N) return;
    int o = i % N, b = i / N;
    float acc = bias[o];
    for (int s = 0; s < S; ++s) acc += partial[((size_t)s * 10 + b) * N + o];
    out[(size_t)b * N + o] = fmaxf(acc, 0.f);
}

// ---------------------------------------------------------------------------
// Final fused: 1x1 convs + geometry (unchanged)
// ---------------------------------------------------------------------------
__global__ __launch_bounds__(256) void final_fused_v2(const float* __restrict__ h,
    const float* __restrict__ xyzw, const float* __restrict__ xyzb,
    const float* __restrict__ maskw, const float* __restrict__ maskb,
    const float* __restrict__ quat, float* __restrict__ out)
{
    const int V = 8, HW = 128 * 128, C = 48, Bn = 10, VHW = V * HW;
    __shared__ float4 sh[48 * 32];
    int b = blockIdx.y, tile = blockIdx.x;
    const float4* hb = (const float4*)h;
    for (int i = threadIdx.x; i < C * 32; i += 256) {
        int ci = i >> 5, p = i & 31;
        sh[i] = hb[(size_t)(b * C + ci) * (HW / 4) + tile * 32 + p];
    }
    __syncthreads();

    int pl = threadIdx.x & 31, v = threadIdx.x >> 5;
    float4 xr = {0,0,0,0}, yr = {0,0,0,0}, zr = {0,0,0,0}, mm = {0,0,0,0};
    const float* wx = xyzw + (size_t)(v * 3 + 0) * C;
    const float* wy = xyzw + (size_t)(v * 3 + 1) * C;
    const float* wz = xyzw + (size_t)(v * 3 + 2) * C;
    const float* wm = maskw + (size_t)v * C;
    for (int ci = 0; ci < C; ++ci) {
        float4 hv = sh[ci * 32 + pl];
        float a;
        a = wx[ci]; xr.x += a*hv.x; xr.y += a*hv.y; xr.z += a*hv.z; xr.w += a*hv.w;
        a = wy[ci]; yr.x += a*hv.x; yr.y += a*hv.y; yr.z += a*hv.z; yr.w += a*hv.w;
        a = wz[ci]; zr.x += a*hv.x; zr.y += a*hv.y; zr.z += a*hv.z; zr.w += a*hv.w;
        a = wm[ci]; mm.x += a*hv.x; mm.y += a*hv.y; mm.z += a*hv.z; mm.w += a*hv.w;
    }
    float bxv = xyzb[v * 3 + 0], byv = xyzb[v * 3 + 1], bzv = xyzb[v * 3 + 2], bmv = maskb[v];

    float qw = quat[v*4+0], qx = quat[v*4+1], qy = quat[v*4+2], qz = quat[v*4+3];
    float R00 = 1.f - 2.f*(qy*qy + qz*qz), R01 = 2.f*(qx*qy - qw*qz), R02 = 2.f*(qx*qz + qw*qy);
    float R10 = 2.f*(qx*qy + qw*qz), R11 = 1.f - 2.f*(qx*qx + qz*qz), R12 = 2.f*(qy*qz - qw*qx);
    float R20 = 2.f*(qx*qz - qw*qy), R21 = 2.f*(qy*qz + qw*qx), R22 = 1.f - 2.f*(qx*qx + qy*qy);

    float4 o0, o1, o2, om;
    float* X = (float*)&xr; float* Y = (float*)&yr; float* Z = (float*)&zr; float* M = (float*)&mm;
    float* O0 = (float*)&o0; float* O1 = (float*)&o1; float* O2 = (float*)&o2; float* OM = (float*)&om;
    #pragma unroll
    for (int j = 0; j < 4; ++j) {
        float camX = (X[j] + bxv) * (1.f / 64.f) - 0.5f;
        float camY = -(Y[j] + byv) * (1.f / 64.f) + 0.5f;
        float camZ = -((Z[j] + bzv) + 1.0f);
        O0[j] = R00 * camX + R10 * camY + R20 * camZ;
        O1[j] = R01 * camX + R11 * camY + R21 * camZ;
        O2[j] = R02 * camX + R12 * camY + R22 * camZ;
        OM[j] = M[j] + bmv;
    }

    size_t o = (size_t)v * HW + tile * 128 + pl * 4;
    float4* op = (float4*)out;
    op[((size_t)(b * 3 + 0) * VHW + o) >> 2] = o0;
    op[((size_t)(b * 3 + 1) * VHW + o) >> 2] = o1;
    op[((size_t)(b * 3 + 2) * VHW + o) >> 2] = o2;
    op[((size_t)Bn * 3 * VHW + (size_t)b * VHW + o) >> 2] = om;
}

// ---------------------------------------------------------------------------

extern "C" void kernel_launch(void* const* d_in, const int* in_sizes, int n_in,
                              void* d_out, int out_size, void* d_ws, size_t ws_size,
                              hipStream_t stream)
{
    const float* x    = (const float*)d_in[0];
    const float* ew0  = (const float*)d_in[1];
    const float* eb0  = (const float*)d_in[2];
    const float* ew1  = (const float*)d_in[3];
    const float* eb1  = (const float*)d_in[4];
    const float* ew2  = (const float*)d_in[5];
    const float* eb2  = (const float*)d_in[6];
    const float* ew3  = (const float*)d_in[7];
    const float* eb3  = (const float*)d_in[8];
    const float* efw  = (const float*)d_in[9];
    const float* efb  = (const float*)d_in[10];
    const float* dfw  = (const float*)d_in[11];
    const float* dfb  = (const float*)d_in[12];
    const float* dw0  = (const float*)d_in[13];
    const float* db0  = (const float*)d_in[14];
    const float* dw1  = (const float*)d_in[15];
    const float* db1  = (const float*)d_in[16];
    const float* dw2  = (const float*)d_in[17];
    const float* db2  = (const float*)d_in[18];
    const float* dw3  = (const float*)d_in[19];
    const float* db3  = (const float*)d_in[20];
    const float* dw4  = (const float*)d_in[21];
    const float* db4  = (const float*)d_in[22];
    const float* xyzw = (const float*)d_in[23];
    const float* xyzb = (const float*)d_in[24];
    const float* maskw= (const float*)d_in[25];
    const float* maskb= (const float*)d_in[26];
    const float* quat = (const float*)d_in[27];
    float* out = (float*)d_out;

    float* A   = (float*)d_ws;
    float* Bb  = A + 7864320;
    float* P1  = A;                       // fc1 partials 655,360
    float* L   = A + 1120000;             // latent 5,120
    float* P2  = Bb + 1000000;            // fc2 partials 655,360
    float* H0  = Bb;                      // fc2 out 40,960 (also conv3 out)
    ushort* Abuf4  = (ushort*)(Bb + 2700000); // d4 A-frags  49,152 ush
    ushort* Abuf3  = (ushort*)(A + 1000000);  // d3 A-frags  98,304 ush
    ushort* Abuf2  = (ushort*)(A + 1200000);  // d2 A-frags 196,608 ush
    ushort* Abuf1  = (ushort*)(A + 1400000);  // d1 A-frags 393,216 ush (ends A+1,596,608 fl)
    ushort* Abuf0  = (ushort*)(A + 1600000);  // d0 A-frags 786,432 ush (ends A+1,993,216 fl)
    ushort* AbufC1 = (ushort*)(A + 2000000);  // conv1 A-frags 110,592 ush
    ushort* AbufC2 = (ushort*)(A + 2100000);  // conv2 A-frags 221,184 ush
    ushort* AbufC3 = (ushort*)(A + 2250000);  // conv3 A-frags 442,368 ush (ends A+2,471,184 fl)
    // audit: conv0 out A[0..983,040]; AbufC* consumed by conv1/2/3 (before fc); P1 written
    // after conv3; d2-mfma writes A[0..983,040]; d4-mfma overwrites all A last; Abuf4 in Bb
    // beyond d3's output span [0..2,621,440].

    const int TB = 256;

    // ONE merged weight-prep kernel (was 8 launches)
    prep_all<<<8976, 256, 0, stream>>>(dw4, dw3, dw2, dw1, dw0, ew1, ew2, ew3,
                                       Abuf4, Abuf3, Abuf2, Abuf1, Abuf0,
                                       AbufC1, AbufC2, AbufC3);

    // encoder
    conv3x3_c3<<<3840, 256, 0, stream>>>(x, ew0, eb0, A);
    conv_mfma_g< 96,128,16><<<dim3(16, 10, 2), 256, 0, stream>>>(A,  AbufC1, eb1, Bb);
    conv_mfma_g<128,192, 8><<<dim3( 4, 10, 3), 256, 0, stream>>>(Bb, AbufC2, eb2, A);
    conv_mfma_g<192,256, 4><<<dim3( 1, 10, 4), 256, 0, stream>>>(A,  AbufC3, eb3, Bb);

    // fc
    fc_splitk<32><<<dim3(2, 128), 256, 0, stream>>>(Bb, efw, P1, 4096, 512);
    fc_reduce_relu<<<CDIV(10 * 512, TB), TB, 0, stream>>>(P1, efb, L, 512, 128);
    fc_splitk<32><<<dim3(16, 16), 256, 0, stream>>>(L, dfw, P2, 512, 4096);
    fc_reduce_relu<<<CDIV(10 * 4096, TB), TB, 0, stream>>>(P2, dfb, H0, 4096, 16);

    // decoder — all bf16 MFMA
    deconv_mfma_d0<<<dim3(1, 10, 4), 256, 0, stream>>>(H0, Abuf0, db0, A);
    // d1: MS=1 (all 8 m-frags per block; 8x less staging redundancy), grid (1,10,4)
    deconv_mfma_g<192,128,  8, 1, 1><<<dim3( 1, 10,  4), 256, 0, stream>>>(A, Abuf1, db1, Bb);
    deconv_mfma_g<128, 96, 16, 1, 3><<<dim3( 4, 10, 12), 256, 0, stream>>>(Bb, Abuf2, db2, A);
    deconv_mfma_g< 96, 64, 32, 1, 1><<<dim3(16, 10,  4), 256, 0, stream>>>(A, Abuf3, db3, Bb);
    deconv_mfma_g< 64, 48, 64, 2, 1><<<dim3(64, 10,  2), 256, 0, stream>>>(Bb, Abuf4, db4, A);

    // fused 1x1 convs + geometry -> d_out
    final_fused_v2<<<dim3(128, 10), 256, 0, stream>>>(A, xyzw, xyzb, maskw, maskb, quat, out);
}

// Round 20
// 305.086 us; speedup vs baseline: 1.1522x; 1.1522x over previous
//
#include <hip/hip_runtime.h>

#define CDIV(a,b) (((a)+(b)-1)/(b))

typedef short short8v __attribute__((ext_vector_type(8)));
typedef float f32x4 __attribute__((ext_vector_type(4)));

__device__ __forceinline__ ushort f2bf(float v) {
    uint u = __float_as_uint(v);
    return (ushort)((u + 0x7FFF + ((u >> 16) & 1)) >> 16);
}

// ---------------------------------------------------------------------------
// conv0: 3->96, 64x64 -> 32x32, fully unrolled (fp32; CIN=3 not MFMA-friendly)
// ---------------------------------------------------------------------------
__global__ __launch_bounds__(256) void conv3x3_c3(const float* __restrict__ in,
    const float* __restrict__ w, const float* __restrict__ bias, float* __restrict__ out)
{
    int idx = blockIdx.x * 256 + threadIdx.x;     // 10*96*32*32 = 983040 exact
    int ox = idx & 31; int t = idx >> 5;
    int oy = t & 31;   t >>= 5;
    int co = t % 96;   int b = t / 96;
    float acc = bias[co];
    const float* wp  = w + co * 27;
    const float* ipb = in + (size_t)b * 3 * 64 * 64;
    #pragma unroll
    for (int ci = 0; ci < 3; ++ci) {
        #pragma unroll
        for (int ky = 0; ky < 3; ++ky) {
            int iy = 2 * oy + ky;
            #pragma unroll
            for (int kx = 0; kx < 3; ++kx) {
                int ix = 2 * ox + kx;
                if (iy < 64 && ix < 64)
                    acc = fmaf(wp[ci * 9 + ky * 3 + kx], ipb[(ci * 64 + iy) * 64 + ix], acc);
            }
        }
    }
    out[idx] = fmaxf(acc, 0.f);
}

// ---------------------------------------------------------------------------
// Packing helpers + ONE merged prep kernel (kept from R18)
// ---------------------------------------------------------------------------
template<int CIN,int COUT>
__device__ __forceinline__ void pack_deconv(const float* __restrict__ w, ushort* __restrict__ Abuf, int idx)
{
    constexpr int MFR = COUT / 16, NSL = CIN / 8;
    int e = idx & 7; int t2 = idx >> 3;
    int lane = t2 & 63; t2 >>= 6;
    int s = t2 % NSL; t2 /= NSL;
    int m = t2 % MFR; int q = t2 / MFR;
    int co = m * 16 + (lane & 15);
    int k = s * 32 + (lane >> 4) * 8 + e;
    int tap = k / CIN, ci = k % CIN;
    const int widx[4][4] = {{5,7,13,15},{4,6,12,14},{1,3,9,11},{0,2,8,10}};
    Abuf[idx] = f2bf(w[((size_t)ci * COUT + co) * 16 + widx[q][tap]]);
}

template<int CIN,int COUT>
__device__ __forceinline__ void pack_conv(const float* __restrict__ w, ushort* __restrict__ Abuf, int idx)
{
    constexpr int NSL = 9 * CIN / 32;
    int e = idx & 7; int t2 = idx >> 3;
    int lane = t2 & 63; t2 >>= 6;
    int s = t2 % NSL; int m = t2 / NSL;
    int co = m * 16 + (lane & 15);
    int k = s * 32 + (lane >> 4) * 8 + e;
    int tap = k / CIN, ci = k % CIN;
    Abuf[idx] = f2bf(w[((size_t)co * CIN + ci) * 9 + tap]);
}

__global__ __launch_bounds__(256) void prep_all(
    const float* __restrict__ dw4, const float* __restrict__ dw3, const float* __restrict__ dw2,
    const float* __restrict__ dw1, const float* __restrict__ dw0,
    const float* __restrict__ ew1, const float* __restrict__ ew2, const float* __restrict__ ew3,
    ushort* A4, ushort* A3, ushort* A2, ushort* A1, ushort* A0,
    ushort* C1, ushort* C2, ushort* C3)
{
    int idx = blockIdx.x * 256 + threadIdx.x;
    if (idx < 49152)  { pack_deconv< 64, 48>(dw4, A4, idx); return; }
    idx -= 49152;
    if (idx < 98304)  { pack_deconv< 96, 64>(dw3, A3, idx); return; }
    idx -= 98304;
    if (idx < 196608) { pack_deconv<128, 96>(dw2, A2, idx); return; }
    idx -= 196608;
    if (idx < 393216) { pack_deconv<192,128>(dw1, A1, idx); return; }
    idx -= 393216;
    if (idx < 786432) { pack_deconv<256,192>(dw0, A0, idx); return; }
    idx -= 786432;
    if (idx < 110592) { pack_conv< 96,128>(ew1, C1, idx); return; }
    idx -= 110592;
    if (idx < 221184) { pack_conv<128,192>(ew2, C2, idx); return; }
    idx -= 221184;
    if (idx < 442368) { pack_conv<192,256>(ew3, C3, idx); return; }
}

// ---------------------------------------------------------------------------
// Conv MFMA main (unchanged)
// ---------------------------------------------------------------------------
template<int CIN,int COUT,int HOUT>
__global__ __launch_bounds__(256) void conv_mfma_g(const float* __restrict__ X,
    const ushort* __restrict__ Abuf, const float* __restrict__ bias, float* __restrict__ out)
{
    constexpr int HIN = 2 * HOUT;
    constexpr int NSL = 9 * CIN / 32, STR = CIN + 8;
    constexpr int TW = HOUT / 4;
    __shared__ __align__(16) ushort Xs[81 * STR];
    __shared__ float sbias[COUT];
    const int tid = threadIdx.x;
    const int oy0 = (blockIdx.x / TW) * 4, ox0 = (blockIdx.x % TW) * 4;
    const int b = blockIdx.y, ms = blockIdx.z;

    const float* Xb = X + (size_t)b * CIN * HIN * HIN;
    for (int i = tid; i < CIN * 81; i += 256) {
        int ci = i / 81, p = i % 81;
        int r = p / 9, c = p % 9;
        int gy = 2 * oy0 + r, gx = 2 * ox0 + c;
        float v = 0.f;
        if (gy < HIN && gx < HIN) v = Xb[((size_t)ci * HIN + gy) * HIN + gx];
        Xs[p * STR + ci] = f2bf(v);
    }
    if (tid < COUT) sbias[tid] = bias[tid];
    __syncthreads();

    const int w = tid >> 6, lane = tid & 63;
    const int ncol = lane & 15, kg = lane >> 4;
    const int r_n = ncol >> 2, c_n = ncol & 3;

    int ptap[9];
    #pragma unroll
    for (int tp = 0; tp < 9; ++tp) {
        int ky = tp / 3, kx = tp % 3;
        ptap[tp] = ((2 * r_n + ky) * 9 + (2 * c_n + kx)) * STR;
    }

    const int m = ms * 4 + w;
    f32x4 acc = {0.f, 0.f, 0.f, 0.f};
    const ushort* ab = Abuf + ((size_t)m * NSL * 64 + lane) * 8;
    #pragma unroll
    for (int s = 0; s < NSL; ++s) {
        short8v a = *(const short8v*)(ab + (size_t)s * 64 * 8);
        int tap = (s * 32) / CIN;
        int ci0 = (s * 32) % CIN + kg * 8;
        short8v bf = *(const short8v*)(&Xs[ptap[tap] + ci0]);
        acc = __builtin_amdgcn_mfma_f32_16x16x32_bf16(a, bf, acc, 0, 0, 0);
    }
    int oy = oy0 + r_n, ox = ox0 + c_n;
    size_t base = ((size_t)(b * COUT + m * 16 + kg * 4) * HOUT + oy) * HOUT + ox;
    #pragma unroll
    for (int jj = 0; jj < 4; ++jj)
        out[base + (size_t)jj * HOUT * HOUT] = fmaxf(acc[jj] + sbias[m * 16 + kg * 4 + jj], 0.f);
}

// ---------------------------------------------------------------------------
// Deconv MFMA main with m-split MS (unchanged)
// ---------------------------------------------------------------------------
template<int CIN,int COUT,int HIN,int QPB,int MS>
__global__ __launch_bounds__(256) void deconv_mfma_g(const float* __restrict__ X,
    const ushort* __restrict__ Abuf, const float* __restrict__ bias, float* __restrict__ out)
{
    constexpr int MFR = COUT / 16, NSL = CIN / 8, STR = CIN + 8;
    constexpr int MPB = MFR / MS;
    constexpr int ZQ = 4 / QPB;
    constexpr int WOUT = 2 * HIN, PLANE = 4 * HIN * HIN;
    __shared__ __align__(16) ushort Xs[100 * STR];
    __shared__ float sbias[COUT];
    const int tid = threadIdx.x;
    constexpr int TW = HIN / 8;
    const int t0 = (blockIdx.x / TW) * 8, u0 = (blockIdx.x % TW) * 8;
    const int b = blockIdx.y;
    const int zq = blockIdx.z % ZQ;
    const int ms = blockIdx.z / ZQ;

    const float* Xb = X + (size_t)b * CIN * HIN * HIN;
    for (int i = tid; i < CIN * 100; i += 256) {
        int ci = i / 100, p = i % 100;
        int r = p / 10, c = p % 10;
        int gt = t0 - 1 + r, gu = u0 - 1 + c;
        float v = 0.f;
        if (gt >= 0 && gt < HIN && gu >= 0 && gu < HIN)
            v = Xb[((size_t)ci * HIN + gt) * HIN + gu];
        Xs[p * STR + ci] = f2bf(v);
    }
    if (tid < COUT) sbias[tid] = bias[tid];
    __syncthreads();

    const int w = tid >> 6, lane = tid & 63;
    const int ncol = lane & 15, kg = lane >> 4;
    const int r_n = 2 * w + (ncol >> 3), c_n = ncol & 7;

    #pragma unroll
    for (int qz = 0; qz < QPB; ++qz) {
        const int q = zq * QPB + qz;
        const int py = q >> 1, px = q & 1;
        int ptap[4];
        #pragma unroll
        for (int tp = 0; tp < 4; ++tp) {
            int dy = py - (tp >> 1);
            int dx = px - (tp & 1);
            ptap[tp] = ((r_n + 1 + dy) * 10 + (c_n + 1 + dx)) * STR;
        }
        #pragma unroll
        for (int mm = 0; mm < MPB; ++mm) {
            const int m = ms * MPB + mm;
            f32x4 acc = {0.f, 0.f, 0.f, 0.f};
            const ushort* ab = Abuf + (((size_t)(q * MFR + m) * NSL) * 64 + lane) * 8;
            #pragma unroll
            for (int s = 0; s < NSL; ++s) {
                short8v a = *(const short8v*)(ab + (size_t)s * 64 * 8);
                int tap = (s * 32) / CIN;
                int ci0 = (s * 32) % CIN + kg * 8;
                short8v bf = *(const short8v*)(&Xs[ptap[tap] + ci0]);
                acc = __builtin_amdgcn_mfma_f32_16x16x32_bf16(a, bf, acc, 0, 0, 0);
            }
            int t = t0 + r_n, u = u0 + c_n;
            size_t base = ((size_t)(b * COUT + m * 16 + kg * 4) * (2 * HIN) + (2 * t + py)) * WOUT + (2 * u + px);
            #pragma unroll
            for (int jj = 0; jj < 4; ++jj) {
                float v = acc[jj] + sbias[m * 16 + kg * 4 + jj];
                out[base + (size_t)jj * PLANE] = fmaxf(v, 0.f);
            }
        }
    }
}

// d0 MFMA (unchanged): whole 4x4 plane = one n-frag; grid (1,10,4)
__global__ __launch_bounds__(256) void deconv_mfma_d0(const float* __restrict__ X,
    const ushort* __restrict__ Abuf, const float* __restrict__ bias, float* __restrict__ out)
{
    constexpr int CIN = 256, COUT = 192, MFR = 12, NSL = 32, STR = CIN + 8;
    __shared__ __align__(16) ushort Xs[36 * STR];
    __shared__ float sbias[COUT];
    const int tid = threadIdx.x;
    const int b = blockIdx.y, q = blockIdx.z;

    const float* Xb = X + (size_t)b * CIN * 16;
    for (int i = tid; i < CIN * 36; i += 256) {
        int ci = i / 36, p = i % 36;
        int r = p / 6, c = p % 6;
        int gt = r - 1, gu = c - 1;
        float v = 0.f;
        if (gt >= 0 && gt < 4 && gu >= 0 && gu < 4)
            v = Xb[(ci * 4 + gt) * 4 + gu];
        Xs[p * STR + ci] = f2bf(v);
    }
    if (tid < COUT) sbias[tid] = bias[tid];
    __syncthreads();

    const int w = tid >> 6, lane = tid & 63;
    const int ncol = lane & 15, kg = lane >> 4;
    const int r_n = ncol >> 2, c_n = ncol & 3;
    const int py = q >> 1, px = q & 1;

    int ptap[4];
    #pragma unroll
    for (int tp = 0; tp < 4; ++tp) {
        int dy = py - (tp >> 1);
        int dx = px - (tp & 1);
        ptap[tp] = ((r_n + 1 + dy) * 6 + (c_n + 1 + dx)) * STR;
    }
    #pragma unroll
    for (int j = 0; j < 3; ++j) {
        const int m = w + 4 * j;
        f32x4 acc = {0.f, 0.f, 0.f, 0.f};
        const ushort* ab = Abuf + (((size_t)(q * MFR + m) * NSL) * 64 + lane) * 8;
        #pragma unroll
        for (int s = 0; s < NSL; ++s) {
            short8v a = *(const short8v*)(ab + (size_t)s * 64 * 8);
            int tap = s >> 3, ci0 = (s & 7) * 32 + kg * 8;
            short8v bf = *(const short8v*)(&Xs[ptap[tap] + ci0]);
            acc = __builtin_amdgcn_mfma_f32_16x16x32_bf16(a, bf, acc, 0, 0, 0);
        }
        size_t base = ((size_t)(b * COUT + m * 16 + kg * 4) * 8 + (2 * r_n + py)) * 8 + (2 * c_n + px);
        #pragma unroll
        for (int jj = 0; jj < 4; ++jj) {
            float v = acc[jj] + sbias[m * 16 + kg * 4 + jj];
            out[base + (size_t)jj * 64] = fmaxf(v, 0.f);
        }
    }
}

// ---------------------------------------------------------------------------
// Split-K FC (unchanged)
// ---------------------------------------------------------------------------
template<int KC>
__global__ __launch_bounds__(256) void fc_splitk(const float* __restrict__ in,
    const float* __restrict__ W, float* __restrict__ partial, int K, int N)
{
    __shared__ float s_in[10 * KC];
    const int o = blockIdx.x * 256 + threadIdx.x;
    const int k0 = blockIdx.y * KC;
    for (int i = threadIdx.x; i < 10 * KC; i += 256) {
        int b = i / KC, k = i % KC;
        s_in[i] = in[(size_t)b * K + k0 + k];
    }
    __syncthreads();

    float acc[10];
    #pragma unroll
    for (int b = 0; b < 10; ++b) acc[b] = 0.f;
    const float* wp = W + (size_t)k0 * N + o;
    #pragma unroll 4
    for (int k = 0; k < KC; ++k) {
        float wv = wp[(size_t)k * N];
        #pragma unroll
        for (int b = 0; b < 10; ++b) acc[b] = fmaf(wv, s_in[b * KC + k], acc[b]);
    }
    float* pp = partial + ((size_t)blockIdx.y * 10) * N + o;
    #pragma unroll
    for (int b = 0; b < 10; ++b) pp[(size_t)b * N] = acc[b];
}

__global__ void fc_reduce_relu(const float* __restrict__ partial, const float* __restrict__ bias,
                               float* __restrict__ out, int N, int S)
{
    int i = blockIdx.x * 256 + threadIdx.x;
    if (i >= 10 * N) return;
    int o = i % N, b = i / N;
    float acc = bias[o];
    for (int s = 0; s < S; ++s) acc += partial[((size_t)s * 10 + b) * N + o];
    out[(size_t)b * N + o] = fmaxf(acc, 0.f);
}

// ---------------------------------------------------------------------------
// Final fused: 1x1 convs + geometry (unchanged)
// ---------------------------------------------------------------------------
__global__ __launch_bounds__(256) void final_fused_v2(const float* __restrict__ h,
    const float* __restrict__ xyzw, const float* __restrict__ xyzb,
    const float* __restrict__ maskw, const float* __restrict__ maskb,
    const float* __restrict__ quat, float* __restrict__ out)
{
    const int V = 8, HW = 128 * 128, C = 48, Bn = 10, VHW = V * HW;
    __shared__ float4 sh[48 * 32];
    int b = blockIdx.y, tile = blockIdx.x;
    const float4* hb = (const float4*)h;
    for (int i = threadIdx.x; i < C * 32; i += 256) {
        int ci = i >> 5, p = i & 31;
        sh[i] = hb[(size_t)(b * C + ci) * (HW / 4) + tile * 32 + p];
    }
    __syncthreads();

    int pl = threadIdx.x & 31, v = threadIdx.x >> 5;
    float4 xr = {0,0,0,0}, yr = {0,0,0,0}, zr = {0,0,0,0}, mm = {0,0,0,0};
    const float* wx = xyzw + (size_t)(v * 3 + 0) * C;
    const float* wy = xyzw + (size_t)(v * 3 + 1) * C;
    const float* wz = xyzw + (size_t)(v * 3 + 2) * C;
    const float* wm = maskw + (size_t)v * C;
    for (int ci = 0; ci < C; ++ci) {
        float4 hv = sh[ci * 32 + pl];
        float a;
        a = wx[ci]; xr.x += a*hv.x; xr.y += a*hv.y; xr.z += a*hv.z; xr.w += a*hv.w;
        a = wy[ci]; yr.x += a*hv.x; yr.y += a*hv.y; yr.z += a*hv.z; yr.w += a*hv.w;
        a = wz[ci]; zr.x += a*hv.x; zr.y += a*hv.y; zr.z += a*hv.z; zr.w += a*hv.w;
        a = wm[ci]; mm.x += a*hv.x; mm.y += a*hv.y; mm.z += a*hv.z; mm.w += a*hv.w;
    }
    float bxv = xyzb[v * 3 + 0], byv = xyzb[v * 3 + 1], bzv = xyzb[v * 3 + 2], bmv = maskb[v];

    float qw = quat[v*4+0], qx = quat[v*4+1], qy = quat[v*4+2], qz = quat[v*4+3];
    float R00 = 1.f - 2.f*(qy*qy + qz*qz), R01 = 2.f*(qx*qy - qw*qz), R02 = 2.f*(qx*qz + qw*qy);
    float R10 = 2.f*(qx*qy + qw*qz), R11 = 1.f - 2.f*(qx*qx + qz*qz), R12 = 2.f*(qy*qz - qw*qx);
    float R20 = 2.f*(qx*qz - qw*qy), R21 = 2.f*(qy*qz + qw*qx), R22 = 1.f - 2.f*(qx*qx + qy*qy);

    float4 o0, o1, o2, om;
    float* X = (float*)&xr; float* Y = (float*)&yr; float* Z = (float*)&zr; float* M = (float*)&mm;
    float* O0 = (float*)&o0; float* O1 = (float*)&o1; float* O2 = (float*)&o2; float* OM = (float*)&om;
    #pragma unroll
    for (int j = 0; j < 4; ++j) {
        float camX = (X[j] + bxv) * (1.f / 64.f) - 0.5f;
        float camY = -(Y[j] + byv) * (1.f / 64.f) + 0.5f;
        float camZ = -((Z[j] + bzv) + 1.0f);
        O0[j] = R00 * camX + R10 * camY + R20 * camZ;
        O1[j] = R01 * camX + R11 * camY + R21 * camZ;
        O2[j] = R02 * camX + R12 * camY + R22 * camZ;
        OM[j] = M[j] + bmv;
    }

    size_t o = (size_t)v * HW + tile * 128 + pl * 4;
    float4* op = (float4*)out;
    op[((size_t)(b * 3 + 0) * VHW + o) >> 2] = o0;
    op[((size_t)(b * 3 + 1) * VHW + o) >> 2] = o1;
    op[((size_t)(b * 3 + 2) * VHW + o) >> 2] = o2;
    op[((size_t)Bn * 3 * VHW + (size_t)b * VHW + o) >> 2] = om;
}

// ---------------------------------------------------------------------------

extern "C" void kernel_launch(void* const* d_in, const int* in_sizes, int n_in,
                              void* d_out, int out_size, void* d_ws, size_t ws_size,
                              hipStream_t stream)
{
    const float* x    = (const float*)d_in[0];
    const float* ew0  = (const float*)d_in[1];
    const float* eb0  = (const float*)d_in[2];
    const float* ew1  = (const float*)d_in[3];
    const float* eb1  = (const float*)d_in[4];
    const float* ew2  = (const float*)d_in[5];
    const float* eb2  = (const float*)d_in[6];
    const float* ew3  = (const float*)d_in[7];
    const float* eb3  = (const float*)d_in[8];
    const float* efw  = (const float*)d_in[9];
    const float* efb  = (const float*)d_in[10];
    const float* dfw  = (const float*)d_in[11];
    const float* dfb  = (const float*)d_in[12];
    const float* dw0  = (const float*)d_in[13];
    const float* db0  = (const float*)d_in[14];
    const float* dw1  = (const float*)d_in[15];
    const float* db1  = (const float*)d_in[16];
    const float* dw2  = (const float*)d_in[17];
    const float* db2  = (const float*)d_in[18];
    const float* dw3  = (const float*)d_in[19];
    const float* db3  = (const float*)d_in[20];
    const float* dw4  = (const float*)d_in[21];
    const float* db4  = (const float*)d_in[22];
    const float* xyzw = (const float*)d_in[23];
    const float* xyzb = (const float*)d_in[24];
    const float* maskw= (const float*)d_in[25];
    const float* maskb= (const float*)d_in[26];
    const float* quat = (const float*)d_in[27];
    float* out = (float*)d_out;

    float* A   = (float*)d_ws;
    float* Bb  = A + 7864320;
    float* P1  = A;                       // fc1 partials 655,360
    float* L   = A + 1120000;             // latent 5,120
    float* P2  = Bb + 1000000;            // fc2 partials 655,360
    float* H0  = Bb;                      // fc2 out 40,960 (also conv3 out)
    ushort* Abuf4  = (ushort*)(Bb + 2700000); // d4 A-frags  49,152 ush
    ushort* Abuf3  = (ushort*)(A + 1000000);  // d3 A-frags  98,304 ush
    ushort* Abuf2  = (ushort*)(A + 1200000);  // d2 A-frags 196,608 ush
    ushort* Abuf1  = (ushort*)(A + 1400000);  // d1 A-frags 393,216 ush (ends A+1,596,608 fl)
    ushort* Abuf0  = (ushort*)(A + 1600000);  // d0 A-frags 786,432 ush (ends A+1,993,216 fl)
    ushort* AbufC1 = (ushort*)(A + 2000000);  // conv1 A-frags 110,592 ush
    ushort* AbufC2 = (ushort*)(A + 2100000);  // conv2 A-frags 221,184 ush
    ushort* AbufC3 = (ushort*)(A + 2250000);  // conv3 A-frags 442,368 ush (ends A+2,471,184 fl)
    // audit: conv0 out A[0..983,040]; AbufC* consumed by conv1/2/3 (before fc); P1 written
    // after conv3; d2-mfma writes A[0..983,040]; d4-mfma overwrites all A last; Abuf4 in Bb
    // beyond d3's output span [0..2,621,440].

    const int TB = 256;

    // ONE merged weight-prep kernel
    prep_all<<<8976, 256, 0, stream>>>(dw4, dw3, dw2, dw1, dw0, ew1, ew2, ew3,
                                       Abuf4, Abuf3, Abuf2, Abuf1, Abuf0,
                                       AbufC1, AbufC2, AbufC3);

    // encoder
    conv3x3_c3<<<3840, 256, 0, stream>>>(x, ew0, eb0, A);
    conv_mfma_g< 96,128,16><<<dim3(16, 10, 2), 256, 0, stream>>>(A,  AbufC1, eb1, Bb);
    conv_mfma_g<128,192, 8><<<dim3( 4, 10, 3), 256, 0, stream>>>(Bb, AbufC2, eb2, A);
    conv_mfma_g<192,256, 4><<<dim3( 1, 10, 4), 256, 0, stream>>>(A,  AbufC3, eb3, Bb);

    // fc
    fc_splitk<32><<<dim3(2, 128), 256, 0, stream>>>(Bb, efw, P1, 4096, 512);
    fc_reduce_relu<<<CDIV(10 * 512, TB), TB, 0, stream>>>(P1, efb, L, 512, 128);
    fc_splitk<32><<<dim3(16, 16), 256, 0, stream>>>(L, dfw, P2, 512, 4096);
    fc_reduce_relu<<<CDIV(10 * 4096, TB), TB, 0, stream>>>(P2, dfb, H0, 4096, 16);

    // decoder — all bf16 MFMA (d1 back to the measured-best MS=8 config)
    deconv_mfma_d0<<<dim3(1, 10, 4), 256, 0, stream>>>(H0, Abuf0, db0, A);
    deconv_mfma_g<192,128,  8, 1, 8><<<dim3( 1, 10, 32), 256, 0, stream>>>(A, Abuf1, db1, Bb);
    deconv_mfma_g<128, 96, 16, 1, 3><<<dim3( 4, 10, 12), 256, 0, stream>>>(Bb, Abuf2, db2, A);
    deconv_mfma_g< 96, 64, 32, 1, 1><<<dim3(16, 10,  4), 256, 0, stream>>>(A, Abuf3, db3, Bb);
    deconv_mfma_g< 64, 48, 64, 2, 1><<<dim3(64, 10,  2), 256, 0, stream>>>(Bb, Abuf4, db4, A);

    // fused 1x1 convs + geometry -> d_out
    final_fused_v2<<<dim3(128, 10), 256, 0, stream>>>(A, xyzw, xyzb, maskw, maskb, quat, out);
}